// Round 1
// baseline (460.667 us; speedup 1.0000x reference)
//
#include <hip/hip_runtime.h>
#include <hip/hip_bf16.h>
#include <math.h>

typedef __bf16 bf16_t;
typedef __bf16 bf16x4_t __attribute__((ext_vector_type(4)));
typedef __bf16 bf16x8_t __attribute__((ext_vector_type(8)));
typedef float  f32x4_t  __attribute__((ext_vector_type(4)));

#define SEQ 2048
#define DM  1024
#define NH  16
#define DK  64
// log2(10000)/32
#define ROPE_C 0.4152410118609203f
// log2(e)/sqrt(dk)
#define EXP_C (1.4426950408889634f / 8.0f)

// ---------------- fp32 -> bf16 cast ----------------
__global__ __launch_bounds__(256)
void cast_kernel(const float* __restrict__ src, bf16_t* __restrict__ dst, int n4) {
  int i = blockIdx.x * 256 + threadIdx.x;
  if (i < n4) {
    float4 v = ((const float4*)src)[i];
    bf16x4_t o;
    o.x = (bf16_t)v.x; o.y = (bf16_t)v.y; o.z = (bf16_t)v.z; o.w = (bf16_t)v.w;
    ((bf16x4_t*)dst)[i] = o;
  }
}

// ---------------- NT GEMM: C[M,N] = A[M,K] * B[N,K]^T + bias ----------------
// M=4096 (B*S), N=1024 (D), K=1024 (D). 128x128 block tile, BK=32, 256 thr.
// FINAL=false: dst is bf16 in (B,H,S,dk) layout, optional fused RoPE.
// FINAL=true : dst is fp32 row-major (M,N).
template<bool FINAL>
__global__ __launch_bounds__(256)
void gemm_nt(const bf16_t* __restrict__ A, const bf16_t* __restrict__ Bw,
             const float* __restrict__ bias, void* __restrict__ dst, int doRope) {
  const int K = 1024;
  __shared__ bf16_t As[128 * 40];   // +8 pad: 2-way bank alias only
  __shared__ bf16_t Bs[128 * 40];

  const int tid  = threadIdx.x;
  const int w    = tid >> 6;
  const int lane = tid & 63;
  const int quad = lane >> 4;
  const int lrow = lane & 15;
  const int wm = (w >> 1) * 64, wn = (w & 1) * 64;
  const int bm = blockIdx.y, bn = blockIdx.x;

  const bf16_t* Ablk = A  + (size_t)(bm * 128) * K;
  const bf16_t* Bblk = Bw + (size_t)(bn * 128) * K;

  f32x4_t acc[4][4] = {};

  const int lr = tid >> 1;            // 0..127 staging row
  const int lc = (tid & 1) * 16;      // 0 or 16 staging col

  for (int k0 = 0; k0 < K; k0 += 32) {
    *(uint4*)(&As[lr * 40 + lc])     = *(const uint4*)(&Ablk[(size_t)lr * K + k0 + lc]);
    *(uint4*)(&As[lr * 40 + lc + 8]) = *(const uint4*)(&Ablk[(size_t)lr * K + k0 + lc + 8]);
    *(uint4*)(&Bs[lr * 40 + lc])     = *(const uint4*)(&Bblk[(size_t)lr * K + k0 + lc]);
    *(uint4*)(&Bs[lr * 40 + lc + 8]) = *(const uint4*)(&Bblk[(size_t)lr * K + k0 + lc + 8]);
    __syncthreads();

    bf16x8_t af[4], bf[4];
#pragma unroll
    for (int mi = 0; mi < 4; mi++)
      af[mi] = *(const bf16x8_t*)(&As[(wm + mi * 16 + lrow) * 40 + quad * 8]);
#pragma unroll
    for (int ni = 0; ni < 4; ni++)
      bf[ni] = *(const bf16x8_t*)(&Bs[(wn + ni * 16 + lrow) * 40 + quad * 8]);
#pragma unroll
    for (int mi = 0; mi < 4; mi++)
#pragma unroll
      for (int ni = 0; ni < 4; ni++)
        acc[mi][ni] = __builtin_amdgcn_mfma_f32_16x16x32_bf16(af[mi], bf[ni], acc[mi][ni], 0, 0, 0);
    __syncthreads();
  }

  const int brow = bm * 128 + wm;
  const int bcol = bn * 128 + wn;

  if (!FINAL) {
    bf16_t* D = (bf16_t*)dst;
#pragma unroll
    for (int ni = 0; ni < 4; ni++) {
      const int col = bcol + ni * 16 + lrow;   // output feature 0..1023
      const float bv = bias[col];
      const int t = col & 63;                  // pos within head
      const int h = col >> 6;                  // head
      const float invf = exp2f(-ROPE_C * (float)(t >> 1));
#pragma unroll
      for (int mi = 0; mi < 4; mi++) {
        f32x4_t v = acc[mi][ni];
#pragma unroll
        for (int r = 0; r < 4; r++) {
          const int row = brow + mi * 16 + quad * 4 + r;  // 0..4095 = b*SEQ+s
          float val = v[r] + bv;
          if (doRope) {
            const int s = row & (SEQ - 1);
            float ang = (float)s * invf;
            float sn, cs;
            sincosf(ang, &sn, &cs);
            float pv = __shfl_xor(val, 1);   // partner column (col^1), all lanes active
            val = (t & 1) ? (val * cs + pv * sn) : (val * cs - pv * sn);
          }
          const int b = row >> 11;
          const int s2 = row & (SEQ - 1);
          const size_t o = (((size_t)(b * NH + h) * SEQ) + s2) * DK + t;
          D[o] = (bf16_t)val;
        }
      }
    }
  } else {
    float* D = (float*)dst;
#pragma unroll
    for (int ni = 0; ni < 4; ni++) {
      const int col = bcol + ni * 16 + lrow;
      const float bv = bias[col];
#pragma unroll
      for (int mi = 0; mi < 4; mi++) {
        f32x4_t v = acc[mi][ni];
#pragma unroll
        for (int r = 0; r < 4; r++) {
          const int row = brow + mi * 16 + quad * 4 + r;
          D[(size_t)row * DM + col] = v[r] + bv;
        }
      }
    }
  }
}

// ---------------- flash attention ----------------
// Q,K,V bf16 (B,H,S,dk). Grid: (S/64, B*H). 4 waves; wave owns 16 q-rows.
// K-tile = 32 keys/step.
__global__ __launch_bounds__(256)
void attn_kernel(const bf16_t* __restrict__ Q, const bf16_t* __restrict__ K,
                 const bf16_t* __restrict__ V, bf16_t* __restrict__ AO) {
  __shared__ bf16_t Ks[32 * 72];      // [key][dk], +8 pad
  __shared__ bf16_t Vt[64 * 40];      // [dk][key] transposed, +8 pad
  __shared__ bf16_t Ps[4][16 * 40];   // per-wave P round-trip

  const int tid  = threadIdx.x;
  const int w    = tid >> 6;
  const int lane = tid & 63;
  const int quad = lane >> 4;
  const int lrow = lane & 15;
  const int bh = blockIdx.y;                  // b*NH+h
  const int q0 = blockIdx.x * 64 + w * 16;    // q-row base for this wave

  const size_t hoff = (size_t)bh * SEQ * DK;
  const bf16_t* Qh = Q + hoff;
  const bf16_t* Kh = K + hoff;
  const bf16_t* Vh = V + hoff;

  // Q fragments (persist across K loop)
  bf16x8_t qf0 = *(const bf16x8_t*)(&Qh[(size_t)(q0 + lrow) * DK + quad * 8]);
  bf16x8_t qf1 = *(const bf16x8_t*)(&Qh[(size_t)(q0 + lrow) * DK + 32 + quad * 8]);

  f32x4_t accO[4] = {};
  float mst[4], lst[4];
#pragma unroll
  for (int r = 0; r < 4; r++) { mst[r] = -1e30f; lst[r] = 0.f; }

  const int skey = tid >> 3;          // 0..31 staging key row
  const int scol = (tid & 7) * 8;     // staging dk col

  for (int kt = 0; kt < SEQ / 32; ++kt) {
    const int kb = kt * 32;
    // stage K tile and transposed V tile
    *(uint4*)(&Ks[skey * 72 + scol]) = *(const uint4*)(&Kh[(size_t)(kb + skey) * DK + scol]);
    bf16x8_t vv = *(const bf16x8_t*)(&Vh[(size_t)(kb + skey) * DK + scol]);
#pragma unroll
    for (int i = 0; i < 8; i++) Vt[(scol + i) * 40 + skey] = vv[i];
    __syncthreads();

    // S = Q K^T : two 16x16 tiles over 32 keys
    f32x4_t sacc[2];
#pragma unroll
    for (int n = 0; n < 2; n++) {
      f32x4_t z = {};
      bf16x8_t kf0 = *(const bf16x8_t*)(&Ks[(n * 16 + lrow) * 72 + quad * 8]);
      bf16x8_t kf1 = *(const bf16x8_t*)(&Ks[(n * 16 + lrow) * 72 + 32 + quad * 8]);
      z = __builtin_amdgcn_mfma_f32_16x16x32_bf16(qf0, kf0, z, 0, 0, 0);
      z = __builtin_amdgcn_mfma_f32_16x16x32_bf16(qf1, kf1, z, 0, 0, 0);
      sacc[n] = z;
    }

    // online softmax (rows = quad*4+r, spread across 16 lanes of the quad)
    float p0s[4], p1s[4];
#pragma unroll
    for (int r = 0; r < 4; r++) {
      float rm = fmaxf(sacc[0][r], sacc[1][r]);
#pragma unroll
      for (int off = 1; off < 16; off <<= 1) rm = fmaxf(rm, __shfl_xor(rm, off));
      const float mnew = fmaxf(mst[r], rm);
      const float alpha = exp2f((mst[r] - mnew) * EXP_C);
      const float p0 = exp2f((sacc[0][r] - mnew) * EXP_C);
      const float p1 = exp2f((sacc[1][r] - mnew) * EXP_C);
      float rs = p0 + p1;
#pragma unroll
      for (int off = 1; off < 16; off <<= 1) rs += __shfl_xor(rs, off);
      lst[r] = lst[r] * alpha + rs;
      mst[r] = mnew;
      p0s[r] = p0; p1s[r] = p1;
#pragma unroll
      for (int nt = 0; nt < 4; nt++) accO[nt][r] *= alpha;
    }

    // P (C-layout) -> LDS -> A-layout
#pragma unroll
    for (int r = 0; r < 4; r++) {
      Ps[w][(quad * 4 + r) * 40 + lrow]      = (bf16_t)p0s[r];
      Ps[w][(quad * 4 + r) * 40 + 16 + lrow] = (bf16_t)p1s[r];
    }
    __syncthreads();

    bf16x8_t pf = *(const bf16x8_t*)(&Ps[w][lrow * 40 + quad * 8]);
#pragma unroll
    for (int nt = 0; nt < 4; nt++) {
      bf16x8_t vf = *(const bf16x8_t*)(&Vt[(nt * 16 + lrow) * 40 + quad * 8]);
      accO[nt] = __builtin_amdgcn_mfma_f32_16x16x32_bf16(pf, vf, accO[nt], 0, 0, 0);
    }
    __syncthreads();
  }

  // epilogue: divide by l, write AO in (B,S,D) row-major bf16
  const int b = bh >> 4, h = bh & 15;
#pragma unroll
  for (int nt = 0; nt < 4; nt++) {
#pragma unroll
    for (int r = 0; r < 4; r++) {
      const int srow = q0 + quad * 4 + r;
      const float val = accO[nt][r] / lst[r];
      const size_t o = ((size_t)(b * SEQ + srow)) * DM + h * DK + nt * 16 + lrow;
      AO[o] = (bf16_t)val;
    }
  }
}

extern "C" void kernel_launch(void* const* d_in, const int* in_sizes, int n_in,
                              void* d_out, int out_size, void* d_ws, size_t ws_size,
                              hipStream_t stream) {
  const float* x  = (const float*)d_in[0];
  const float* wq = (const float*)d_in[1];
  const float* bq = (const float*)d_in[2];
  const float* wk = (const float*)d_in[3];
  const float* bk = (const float*)d_in[4];
  const float* wv = (const float*)d_in[5];
  const float* bv = (const float*)d_in[6];
  const float* wo = (const float*)d_in[7];
  const float* bo = (const float*)d_in[8];
  float* out = (float*)d_out;

  char* ws = (char*)d_ws;
  // layout (bytes): xb 8M | wqb/wkb/wvb/wob 2M each | Q/K/V 8M each | AO 8M  => 48 MB
  bf16_t* xb  = (bf16_t*)(ws);
  bf16_t* wqb = (bf16_t*)(ws + 8388608);
  bf16_t* wkb = (bf16_t*)(ws + 10485760);
  bf16_t* wvb = (bf16_t*)(ws + 12582912);
  bf16_t* wob = (bf16_t*)(ws + 14680064);
  bf16_t* Qb  = (bf16_t*)(ws + 16777216);
  bf16_t* Kb  = (bf16_t*)(ws + 25165824);
  bf16_t* Vb  = (bf16_t*)(ws + 33554432);
  bf16_t* AOb = (bf16_t*)(ws + 41943040);

  cast_kernel<<<4096, 256, 0, stream>>>(x,  xb,  (2 * SEQ * DM) / 4);
  cast_kernel<<<1024, 256, 0, stream>>>(wq, wqb, (DM * DM) / 4);
  cast_kernel<<<1024, 256, 0, stream>>>(wk, wkb, (DM * DM) / 4);
  cast_kernel<<<1024, 256, 0, stream>>>(wv, wvb, (DM * DM) / 4);
  cast_kernel<<<1024, 256, 0, stream>>>(wo, wob, (DM * DM) / 4);

  dim3 gg(DM / 128, (2 * SEQ) / 128, 1);   // (8, 32)
  gemm_nt<false><<<gg, 256, 0, stream>>>(xb, wqb, bq, (void*)Qb, 1);
  gemm_nt<false><<<gg, 256, 0, stream>>>(xb, wkb, bk, (void*)Kb, 1);
  gemm_nt<false><<<gg, 256, 0, stream>>>(xb, wvb, bv, (void*)Vb, 0);

  attn_kernel<<<dim3(SEQ / 64, 2 * NH), 256, 0, stream>>>(Qb, Kb, Vb, AOb);

  gemm_nt<true><<<gg, 256, 0, stream>>>(AOb, wob, bo, (void*)out, 0);
}

// Round 2
// 417.826 us; speedup vs baseline: 1.1025x; 1.1025x over previous
//
#include <hip/hip_runtime.h>
#include <hip/hip_bf16.h>
#include <math.h>

typedef __bf16 bf16_t;
typedef __bf16 bf16x4_t __attribute__((ext_vector_type(4)));
typedef __bf16 bf16x8_t __attribute__((ext_vector_type(8)));
typedef float  f32x4_t  __attribute__((ext_vector_type(4)));

#define SEQ 2048
#define DM  1024
#define NH  16
#define DK  64
// log2(10000)/32
#define ROPE_C 0.4152410118609203f
// log2(e)/sqrt(dk)
#define EXP_C (1.4426950408889634f / 8.0f)

// ---------------- fp32 -> bf16 cast ----------------
__global__ __launch_bounds__(256)
void cast_kernel(const float* __restrict__ src, bf16_t* __restrict__ dst, int n4) {
  int i = blockIdx.x * 256 + threadIdx.x;
  if (i < n4) {
    float4 v = ((const float4*)src)[i];
    bf16x4_t o;
    o.x = (bf16_t)v.x; o.y = (bf16_t)v.y; o.z = (bf16_t)v.z; o.w = (bf16_t)v.w;
    ((bf16x4_t*)dst)[i] = o;
  }
}

// ---------------- NT GEMM: C[M,N] = A[M,K] * B[N,K]^T + bias ----------------
// 128x128 block tile, BK=32, 256 thr.
// MODE 0: dst bf16 (B,H,S,dk) [rows=tokens, cols=features], optional RoPE.
// MODE 1: dst fp32 row-major (M=tokens, N=features).
// MODE 2: dst bf16 (B,H,dk,S) "V^T" [rows=features, cols=tokens].
template<int MODE>
__global__ __launch_bounds__(256)
void gemm_nt(const bf16_t* __restrict__ A, const bf16_t* __restrict__ Bw,
             const float* __restrict__ bias, void* __restrict__ dst, int doRope) {
  const int K = 1024;
  __shared__ bf16_t As[128 * 40];   // +8 pad: 2-way bank alias only
  __shared__ bf16_t Bs[128 * 40];

  const int tid  = threadIdx.x;
  const int w    = tid >> 6;
  const int lane = tid & 63;
  const int quad = lane >> 4;
  const int lrow = lane & 15;
  const int wm = (w >> 1) * 64, wn = (w & 1) * 64;
  const int bm = blockIdx.y, bn = blockIdx.x;

  const bf16_t* Ablk = A  + (size_t)(bm * 128) * K;
  const bf16_t* Bblk = Bw + (size_t)(bn * 128) * K;

  f32x4_t acc[4][4] = {};

  const int lr = tid >> 1;            // 0..127 staging row
  const int lc = (tid & 1) * 16;      // 0 or 16 staging col

  for (int k0 = 0; k0 < K; k0 += 32) {
    *(uint4*)(&As[lr * 40 + lc])     = *(const uint4*)(&Ablk[(size_t)lr * K + k0 + lc]);
    *(uint4*)(&As[lr * 40 + lc + 8]) = *(const uint4*)(&Ablk[(size_t)lr * K + k0 + lc + 8]);
    *(uint4*)(&Bs[lr * 40 + lc])     = *(const uint4*)(&Bblk[(size_t)lr * K + k0 + lc]);
    *(uint4*)(&Bs[lr * 40 + lc + 8]) = *(const uint4*)(&Bblk[(size_t)lr * K + k0 + lc + 8]);
    __syncthreads();

    bf16x8_t af[4], bf[4];
#pragma unroll
    for (int mi = 0; mi < 4; mi++)
      af[mi] = *(const bf16x8_t*)(&As[(wm + mi * 16 + lrow) * 40 + quad * 8]);
#pragma unroll
    for (int ni = 0; ni < 4; ni++)
      bf[ni] = *(const bf16x8_t*)(&Bs[(wn + ni * 16 + lrow) * 40 + quad * 8]);
#pragma unroll
    for (int mi = 0; mi < 4; mi++)
#pragma unroll
      for (int ni = 0; ni < 4; ni++)
        acc[mi][ni] = __builtin_amdgcn_mfma_f32_16x16x32_bf16(af[mi], bf[ni], acc[mi][ni], 0, 0, 0);
    __syncthreads();
  }

  const int brow = bm * 128 + wm;
  const int bcol = bn * 128 + wn;

  if (MODE == 0) {
    bf16_t* D = (bf16_t*)dst;
#pragma unroll
    for (int ni = 0; ni < 4; ni++) {
      const int col = bcol + ni * 16 + lrow;   // output feature 0..1023
      const float bv = bias[col];
      const int t = col & 63;                  // pos within head
      const int h = col >> 6;                  // head
      const float invf = exp2f(-ROPE_C * (float)(t >> 1));
#pragma unroll
      for (int mi = 0; mi < 4; mi++) {
        f32x4_t v = acc[mi][ni];
#pragma unroll
        for (int r = 0; r < 4; r++) {
          const int row = brow + mi * 16 + quad * 4 + r;  // 0..4095 = b*SEQ+s
          float val = v[r] + bv;
          if (doRope) {
            const int s = row & (SEQ - 1);
            float ang = (float)s * invf;
            float sn, cs;
            sincosf(ang, &sn, &cs);
            float pv = __shfl_xor(val, 1);   // partner column (col^1), all lanes active
            val = (t & 1) ? (val * cs + pv * sn) : (val * cs - pv * sn);
          }
          const int b = row >> 11;
          const int s2 = row & (SEQ - 1);
          const size_t o = (((size_t)(b * NH + h) * SEQ) + s2) * DK + t;
          D[o] = (bf16_t)val;
        }
      }
    }
  } else if (MODE == 1) {
    float* D = (float*)dst;
#pragma unroll
    for (int ni = 0; ni < 4; ni++) {
      const int col = bcol + ni * 16 + lrow;
      const float bv = bias[col];
#pragma unroll
      for (int mi = 0; mi < 4; mi++) {
        f32x4_t v = acc[mi][ni];
#pragma unroll
        for (int r = 0; r < 4; r++) {
          const int row = brow + mi * 16 + quad * 4 + r;
          D[(size_t)row * DM + col] = v[r] + bv;
        }
      }
    }
  } else {
    // MODE 2: rows = features (A=Wv), cols = tokens (B=x). D = V^T (B,H,dk,S)
    bf16_t* D = (bf16_t*)dst;
#pragma unroll
    for (int ni = 0; ni < 4; ni++) {
      const int t = bcol + ni * 16 + lrow;     // token 0..4095
      const int b = t >> 11;
      const int s = t & (SEQ - 1);
#pragma unroll
      for (int mi = 0; mi < 4; mi++) {
        f32x4_t v = acc[mi][ni];
#pragma unroll
        for (int r = 0; r < 4; r++) {
          const int f = brow + mi * 16 + quad * 4 + r;  // feature 0..1023
          const int h = f >> 6, d = f & 63;
          const size_t o = ((size_t)((b * NH + h) * DK + d)) * SEQ + s;
          D[o] = (bf16_t)(v[r] + bias[f]);
        }
      }
    }
  }
}

// ---------------- flash attention v2 ----------------
// Q,K bf16 (B,H,S,dk); Vt bf16 (B,H,dk,S). Grid: (S/128, B*H). 4 waves;
// wave owns 32 q-rows (2 m-tiles). K-tile = 64 keys/step.
__global__ __launch_bounds__(256)
void attn_kernel(const bf16_t* __restrict__ Q, const bf16_t* __restrict__ K,
                 const bf16_t* __restrict__ Vt, bf16_t* __restrict__ AO) {
  __shared__ bf16_t Ks[64 * 72];      // [key][dk], +8 pad
  __shared__ bf16_t Vs[64 * 72];      // [dk][key], +8 pad (V already transposed)
  __shared__ bf16_t Ps[4][32 * 68];   // per-wave P round-trip, stride 68

  const int tid  = threadIdx.x;
  const int w    = tid >> 6;
  const int lane = tid & 63;
  const int quad = lane >> 4;
  const int lrow = lane & 15;
  const int bh = blockIdx.y;                   // b*NH+h
  const int q0 = blockIdx.x * 128 + w * 32;    // q-row base for this wave

  const bf16_t* Qh  = Q  + (size_t)bh * SEQ * DK;
  const bf16_t* Kh  = K  + (size_t)bh * SEQ * DK;
  const bf16_t* Vth = Vt + (size_t)bh * DK * SEQ;

  // Q fragments (persist across K loop): [mi][k-chunk]
  bf16x8_t qf[2][2];
#pragma unroll
  for (int mi = 0; mi < 2; mi++)
#pragma unroll
    for (int c = 0; c < 2; c++)
      qf[mi][c] = *(const bf16x8_t*)(&Qh[(size_t)(q0 + mi * 16 + lrow) * DK + c * 32 + quad * 8]);

  f32x4_t accO[2][4] = {};
  float mst[2][4], lst[2][4];
#pragma unroll
  for (int mi = 0; mi < 2; mi++)
#pragma unroll
    for (int r = 0; r < 4; r++) { mst[mi][r] = -1e30f; lst[mi][r] = 0.f; }

  const int srow = tid >> 2;          // 0..63 staging row
  const int scol = (tid & 3) * 16;    // staging col chunk

  for (int kt = 0; kt < SEQ / 64; ++kt) {
    const int kb = kt * 64;
    // stage K [key][dk] and V^T [dk][key] — both coalesced uint4
    *(uint4*)(&Ks[srow * 72 + scol])     = *(const uint4*)(&Kh[(size_t)(kb + srow) * DK + scol]);
    *(uint4*)(&Ks[srow * 72 + scol + 8]) = *(const uint4*)(&Kh[(size_t)(kb + srow) * DK + scol + 8]);
    *(uint4*)(&Vs[srow * 72 + scol])     = *(const uint4*)(&Vth[(size_t)srow * SEQ + kb + scol]);
    *(uint4*)(&Vs[srow * 72 + scol + 8]) = *(const uint4*)(&Vth[(size_t)srow * SEQ + kb + scol + 8]);
    __syncthreads();

    // K fragments: [n-tile][k-chunk]
    bf16x8_t kf[4][2];
#pragma unroll
    for (int n = 0; n < 4; n++)
#pragma unroll
      for (int c = 0; c < 2; c++)
        kf[n][c] = *(const bf16x8_t*)(&Ks[(n * 16 + lrow) * 72 + c * 32 + quad * 8]);

    // S = Q K^T, online softmax, P -> LDS (per m-tile)
#pragma unroll
    for (int mi = 0; mi < 2; mi++) {
      f32x4_t sacc[4];
#pragma unroll
      for (int n = 0; n < 4; n++) {
        f32x4_t z = {};
        z = __builtin_amdgcn_mfma_f32_16x16x32_bf16(qf[mi][0], kf[n][0], z, 0, 0, 0);
        z = __builtin_amdgcn_mfma_f32_16x16x32_bf16(qf[mi][1], kf[n][1], z, 0, 0, 0);
        sacc[n] = z;
      }
#pragma unroll
      for (int r = 0; r < 4; r++) {
        float rm = fmaxf(fmaxf(sacc[0][r], sacc[1][r]), fmaxf(sacc[2][r], sacc[3][r]));
#pragma unroll
        for (int off = 1; off < 16; off <<= 1) rm = fmaxf(rm, __shfl_xor(rm, off));
        const float mnew = fmaxf(mst[mi][r], rm);
        const float alpha = exp2f((mst[mi][r] - mnew) * EXP_C);
        float p[4], rs;
#pragma unroll
        for (int n = 0; n < 4; n++) p[n] = exp2f((sacc[n][r] - mnew) * EXP_C);
        rs = (p[0] + p[1]) + (p[2] + p[3]);
#pragma unroll
        for (int off = 1; off < 16; off <<= 1) rs += __shfl_xor(rs, off);
        lst[mi][r] = lst[mi][r] * alpha + rs;
        mst[mi][r] = mnew;
#pragma unroll
        for (int nt = 0; nt < 4; nt++) accO[mi][nt][r] *= alpha;
        const int prow = mi * 16 + quad * 4 + r;
#pragma unroll
        for (int n = 0; n < 4; n++)
          Ps[w][prow * 68 + n * 16 + lrow] = (bf16_t)p[n];
      }
    }

    // P (A-layout) fragments: [mi][k-chunk] — stride 68*2B is 8B-aligned, 2x b64
    bf16x8_t pf[2][2];
#pragma unroll
    for (int mi = 0; mi < 2; mi++)
#pragma unroll
      for (int c = 0; c < 2; c++) {
        const int base = (mi * 16 + lrow) * 68 + c * 32 + quad * 8;
        bf16x8_t t;
        *(bf16x4_t*)(&t)     = *(const bf16x4_t*)(&Ps[w][base]);
        *((bf16x4_t*)(&t)+1) = *(const bf16x4_t*)(&Ps[w][base + 4]);
        pf[mi][c] = t;
      }

    // O += P V
#pragma unroll
    for (int c = 0; c < 2; c++)
#pragma unroll
      for (int nt = 0; nt < 4; nt++) {
        bf16x8_t vf = *(const bf16x8_t*)(&Vs[(nt * 16 + lrow) * 72 + c * 32 + quad * 8]);
        accO[0][nt] = __builtin_amdgcn_mfma_f32_16x16x32_bf16(pf[0][c], vf, accO[0][nt], 0, 0, 0);
        accO[1][nt] = __builtin_amdgcn_mfma_f32_16x16x32_bf16(pf[1][c], vf, accO[1][nt], 0, 0, 0);
      }
    __syncthreads();
  }

  // epilogue: divide by l, write AO in (B,S,D) row-major bf16
  const int b = bh >> 4, h = bh & 15;
#pragma unroll
  for (int mi = 0; mi < 2; mi++)
#pragma unroll
    for (int nt = 0; nt < 4; nt++)
#pragma unroll
      for (int r = 0; r < 4; r++) {
        const int srowq = q0 + mi * 16 + quad * 4 + r;
        const float val = accO[mi][nt][r] / lst[mi][r];
        const size_t o = ((size_t)(b * SEQ + srowq)) * DM + h * DK + nt * 16 + lrow;
        AO[o] = (bf16_t)val;
      }
}

extern "C" void kernel_launch(void* const* d_in, const int* in_sizes, int n_in,
                              void* d_out, int out_size, void* d_ws, size_t ws_size,
                              hipStream_t stream) {
  const float* x  = (const float*)d_in[0];
  const float* wq = (const float*)d_in[1];
  const float* bq = (const float*)d_in[2];
  const float* wk = (const float*)d_in[3];
  const float* bk = (const float*)d_in[4];
  const float* wv = (const float*)d_in[5];
  const float* bv = (const float*)d_in[6];
  const float* wo = (const float*)d_in[7];
  const float* bo = (const float*)d_in[8];
  float* out = (float*)d_out;

  char* ws = (char*)d_ws;
  // layout (bytes): xb 8M | wqb/wkb/wvb/wob 2M each | Q/K/Vt 8M each | AO 8M => 48 MB
  bf16_t* xb  = (bf16_t*)(ws);
  bf16_t* wqb = (bf16_t*)(ws + 8388608);
  bf16_t* wkb = (bf16_t*)(ws + 10485760);
  bf16_t* wvb = (bf16_t*)(ws + 12582912);
  bf16_t* wob = (bf16_t*)(ws + 14680064);
  bf16_t* Qb  = (bf16_t*)(ws + 16777216);
  bf16_t* Kb  = (bf16_t*)(ws + 25165824);
  bf16_t* Vtb = (bf16_t*)(ws + 33554432);
  bf16_t* AOb = (bf16_t*)(ws + 41943040);

  cast_kernel<<<4096, 256, 0, stream>>>(x,  xb,  (2 * SEQ * DM) / 4);
  cast_kernel<<<1024, 256, 0, stream>>>(wq, wqb, (DM * DM) / 4);
  cast_kernel<<<1024, 256, 0, stream>>>(wk, wkb, (DM * DM) / 4);
  cast_kernel<<<1024, 256, 0, stream>>>(wv, wvb, (DM * DM) / 4);
  cast_kernel<<<1024, 256, 0, stream>>>(wo, wob, (DM * DM) / 4);

  dim3 gg(DM / 128, (2 * SEQ) / 128, 1);   // (8, 32): rows=tokens, cols=features
  gemm_nt<0><<<gg, 256, 0, stream>>>(xb, wqb, bq, (void*)Qb, 1);
  gemm_nt<0><<<gg, 256, 0, stream>>>(xb, wkb, bk, (void*)Kb, 1);
  // V^T: A = Wv (rows=features), B = x (cols=tokens)
  dim3 gv((2 * SEQ) / 128, DM / 128, 1);   // (32, 8)
  gemm_nt<2><<<gv, 256, 0, stream>>>(wvb, xb, bv, (void*)Vtb, 0);

  attn_kernel<<<dim3(SEQ / 128, 2 * NH), 256, 0, stream>>>(Qb, Kb, Vtb, AOb);

  gemm_nt<1><<<gg, 256, 0, stream>>>(AOb, wob, bo, (void*)out, 0);
}